// Round 1
// baseline (1022.439 us; speedup 1.0000x reference)
//
#include <hip/hip_runtime.h>
#include <hip/hip_bf16.h>
#include <math.h>

// GAT 2-layer: N=50000, IN=512, H=8, C1=8 (H*C1=64), OUT=64, slope=0.2
// Strategy: CSR-by-dst build (count/scan/scatter), then wave-per-node
// atomic-free segment softmax + aggregation. GEMMs are LDS-tiled fp32.

#define WAVE 64

__device__ inline float wred_sum(float v) {
#pragma unroll
    for (int off = 32; off > 0; off >>= 1) v += __shfl_xor(v, off);
    return v;
}
__device__ inline float wred_max(float v) {
#pragma unroll
    for (int off = 32; off > 0; off >>= 1) v = fmaxf(v, __shfl_xor(v, off));
    return v;
}

// ---------------- CSR build ----------------
__global__ __launch_bounds__(256) void count_deg(const int* __restrict__ ei,
                                                 int* __restrict__ deg, int E, int n) {
    int e = blockIdx.x * 256 + threadIdx.x;
    if (e < E + n) {
        int d = (e < E) ? ei[E + e] : (e - E);   // self-loop dst = node id
        atomicAdd(&deg[d], 1);
    }
}

// single-block exclusive scan over n counters -> rowptr[n+1]
__global__ __launch_bounds__(1024) void scan_deg(const int* __restrict__ deg,
                                                 int* __restrict__ rowptr, int n) {
    __shared__ int part[1024];
    int tid = threadIdx.x;
    int chunk = (n + 1023) >> 10;
    int b = tid * chunk;
    int e = min(b + chunk, n);
    int s = 0;
    for (int i = b; i < e; ++i) s += deg[i];
    part[tid] = s;
    __syncthreads();
    // Hillis-Steele inclusive scan
    for (int off = 1; off < 1024; off <<= 1) {
        int v = (tid >= off) ? part[tid - off] : 0;
        __syncthreads();
        part[tid] += v;
        __syncthreads();
    }
    int run = (tid == 0) ? 0 : part[tid - 1];
    for (int i = b; i < e; ++i) { rowptr[i] = run; run += deg[i]; }
    if (tid == 1023) rowptr[n] = run;
}

__global__ __launch_bounds__(256) void scatter_edges(const int* __restrict__ ei,
                                                     const int* __restrict__ rowptr,
                                                     int* __restrict__ cursor,
                                                     int* __restrict__ csrc, int E, int n) {
    int e = blockIdx.x * 256 + threadIdx.x;
    if (e < E + n) {
        int s, d;
        if (e < E) { s = ei[e]; d = ei[E + e]; }
        else       { s = e - E; d = s; }
        int pos = rowptr[d] + atomicAdd(&cursor[d], 1);
        csrc[pos] = s;
    }
}

// ---------------- GEMM: O[n][64] = X[n][:K] @ W[:K][64] ----------------
__global__ __launch_bounds__(256) void gemm64(const float* __restrict__ X,
                                              const float* __restrict__ W,
                                              float* __restrict__ O, int nrows, int K) {
    __shared__ float xs[32][68];   // transposed x tile: xs[k][m]
    __shared__ float ws[32][68];   // ws[k][ncol]
    int tid = threadIdx.x;
    int bm = blockIdx.x * 64;
    int tx = tid & 15;             // col quad
    int ty = tid >> 4;             // row quad
    float acc[4][4] = {{0.f}};
    for (int k0 = 0; k0 < K; k0 += 32) {
#pragma unroll
        for (int i = 0; i < 2; ++i) {
            int p = tid + i * 256;       // float4 slot among 512
            int row = p >> 3, k4 = p & 7;
            float4 v = {0.f, 0.f, 0.f, 0.f};
            if (bm + row < nrows)
                v = *(const float4*)(X + (size_t)(bm + row) * K + k0 + k4 * 4);
            xs[k4 * 4 + 0][row] = v.x; xs[k4 * 4 + 1][row] = v.y;
            xs[k4 * 4 + 2][row] = v.z; xs[k4 * 4 + 3][row] = v.w;
        }
#pragma unroll
        for (int i = 0; i < 2; ++i) {
            int p = tid + i * 256;
            int kr = p >> 4, c4 = p & 15;
            float4 v = *(const float4*)(W + (size_t)(k0 + kr) * 64 + c4 * 4);
            ws[kr][c4 * 4 + 0] = v.x; ws[kr][c4 * 4 + 1] = v.y;
            ws[kr][c4 * 4 + 2] = v.z; ws[kr][c4 * 4 + 3] = v.w;
        }
        __syncthreads();
#pragma unroll
        for (int kk = 0; kk < 32; ++kk) {
            float a[4], b[4];
#pragma unroll
            for (int i = 0; i < 4; ++i) a[i] = xs[kk][ty * 4 + i];
#pragma unroll
            for (int j = 0; j < 4; ++j) b[j] = ws[kk][tx * 4 + j];
#pragma unroll
            for (int i = 0; i < 4; ++i)
#pragma unroll
                for (int j = 0; j < 4; ++j) acc[i][j] = fmaf(a[i], b[j], acc[i][j]);
        }
        __syncthreads();
    }
    int row0 = bm + ty * 4;
#pragma unroll
    for (int i = 0; i < 4; ++i) {
        int r = row0 + i;
        if (r < nrows) {
            float4 v = {acc[i][0], acc[i][1], acc[i][2], acc[i][3]};
            *(float4*)(O + (size_t)r * 64 + tx * 4) = v;
        }
    }
}

// ---------------- layer-1 attention coefficients ----------------
__global__ __launch_bounds__(256) void alpha1_kernel(const float* __restrict__ H1,
                                                     const float* __restrict__ as1,
                                                     const float* __restrict__ ad1,
                                                     float* __restrict__ asrc,
                                                     float* __restrict__ adst, int n) {
    int idx = blockIdx.x * 256 + threadIdx.x;
    if (idx >= n * 8) return;
    int h = idx & 7;
    const float* hp = H1 + (size_t)(idx >> 3) * 64 + h * 8;
    float s = 0.f, d = 0.f;
#pragma unroll
    for (int c = 0; c < 8; ++c) {
        float v = hp[c];
        s = fmaf(v, as1[h * 8 + c], s);
        d = fmaf(v, ad1[h * 8 + c], d);
    }
    asrc[idx] = s;
    adst[idx] = d;
}

// ---------------- layer-2 attention coefficients (wave per node) ----------------
__global__ __launch_bounds__(256) void alpha2_kernel(const float* __restrict__ H2,
                                                     const float* __restrict__ as2,
                                                     const float* __restrict__ ad2,
                                                     float* __restrict__ asrc,
                                                     float* __restrict__ adst, int n) {
    int node = blockIdx.x * 4 + (threadIdx.x >> 6);
    int lane = threadIdx.x & 63;
    if (node >= n) return;
    float v = H2[(size_t)node * 64 + lane];
    float s = wred_sum(v * as2[lane]);
    float d = wred_sum(v * ad2[lane]);
    if (lane == 0) { asrc[node] = s; adst[node] = d; }
}

// ---------------- layer-1 aggregation: wave per dst node ----------------
__global__ __launch_bounds__(256) void agg1_kernel(const float* __restrict__ H1,
                                                   const float* __restrict__ asrc,
                                                   const float* __restrict__ adst,
                                                   const int* __restrict__ rowptr,
                                                   const int* __restrict__ csrc,
                                                   const float* __restrict__ b1,
                                                   float* __restrict__ out1, int n) {
    int node = blockIdx.x * 4 + (threadIdx.x >> 6);
    int lane = threadIdx.x & 63;
    if (node >= n) return;
    int h = lane >> 3;                        // head of this channel
    int beg = rowptr[node], end = rowptr[node + 1];
    float ad = adst[node * 8 + h];
    // pass A: online max / sum-exp per head (8 lanes per head redundant)
    float m = -1e30f, l = 0.f;
    for (int e = beg; e < end; ++e) {
        int s = csrc[e];
        float t = asrc[s * 8 + h] + ad;
        t = t > 0.f ? t : 0.2f * t;
        float mn = fmaxf(m, t);
        l = l * __expf(m - mn) + __expf(t - mn);
        m = mn;
    }
    float linv = 1.f / (l + 1e-16f);
    // pass B: weighted accumulate
    float acc = 0.f;
    for (int e = beg; e < end; ++e) {
        int s = csrc[e];
        float t = asrc[s * 8 + h] + ad;
        t = t > 0.f ? t : 0.2f * t;
        acc = fmaf(H1[(size_t)s * 64 + lane], __expf(t - m) * linv, acc);
    }
    float o = acc + b1[lane];
    out1[(size_t)node * 64 + lane] = o > 0.f ? o : expm1f(o);   // ELU
}

// ---------------- layer-2 aggregation + log_softmax ----------------
__global__ __launch_bounds__(256) void agg2_kernel(const float* __restrict__ H2,
                                                   const float* __restrict__ asrc,
                                                   const float* __restrict__ adst,
                                                   const int* __restrict__ rowptr,
                                                   const int* __restrict__ csrc,
                                                   const float* __restrict__ b2,
                                                   float* __restrict__ out, int n) {
    int node = blockIdx.x * 4 + (threadIdx.x >> 6);
    int lane = threadIdx.x & 63;
    if (node >= n) return;
    int beg = rowptr[node], end = rowptr[node + 1];
    float ad = adst[node];
    float m = -1e30f, l = 0.f;
    for (int e = beg; e < end; ++e) {
        float t = asrc[csrc[e]] + ad;
        t = t > 0.f ? t : 0.2f * t;
        float mn = fmaxf(m, t);
        l = l * __expf(m - mn) + __expf(t - mn);
        m = mn;
    }
    float linv = 1.f / (l + 1e-16f);
    float acc = 0.f;
    for (int e = beg; e < end; ++e) {
        int s = csrc[e];
        float t = asrc[s] + ad;
        t = t > 0.f ? t : 0.2f * t;
        acc = fmaf(H2[(size_t)s * 64 + lane], __expf(t - m) * linv, acc);
    }
    float o = acc + b2[lane];
    // log_softmax over 64 channels (one wave = one row)
    float mx = wred_max(o);
    float se = wred_sum(__expf(o - mx));
    out[(size_t)node * 64 + lane] = o - mx - logf(se);
}

extern "C" void kernel_launch(void* const* d_in, const int* in_sizes, int n_in,
                              void* d_out, int out_size, void* d_ws, size_t ws_size,
                              hipStream_t stream) {
    const float* x   = (const float*)d_in[0];
    const int*   ei  = (const int*)d_in[1];
    const float* W1  = (const float*)d_in[2];
    const float* as1 = (const float*)d_in[3];
    const float* ad1 = (const float*)d_in[4];
    const float* b1  = (const float*)d_in[5];
    const float* W2  = (const float*)d_in[6];
    const float* as2 = (const float*)d_in[7];
    const float* ad2 = (const float*)d_in[8];
    const float* b2  = (const float*)d_in[9];
    float* out = (float*)d_out;

    const int n  = in_sizes[0] / 512;   // 50000
    const int E  = in_sizes[1] / 2;     // 1600000
    const int Et = E + n;

    // workspace layout (256B-aligned slices)
    char* w = (char*)d_ws;
    auto alloc = [&](size_t bytes) {
        char* p = w;
        w += (bytes + 255) & ~(size_t)255;
        return p;
    };
    int*   deg    = (int*)alloc((size_t)2 * n * 4);   // deg + cursor contiguous
    int*   cursor = deg + n;
    int*   rowptr = (int*)alloc((size_t)(n + 1) * 4);
    int*   csrc   = (int*)alloc((size_t)Et * 4);
    float* h1     = (float*)alloc((size_t)n * 64 * 4);
    float* out1   = (float*)alloc((size_t)n * 64 * 4);
    float* h2     = (float*)alloc((size_t)n * 64 * 4);
    float* asrc1  = (float*)alloc((size_t)n * 8 * 4);
    float* adst1  = (float*)alloc((size_t)n * 8 * 4);
    float* asrc2  = (float*)alloc((size_t)n * 4);
    float* adst2  = (float*)alloc((size_t)n * 4);

    // --- CSR build ---
    hipMemsetAsync(deg, 0, (size_t)2 * n * 4, stream);
    count_deg<<<(Et + 255) / 256, 256, 0, stream>>>(ei, deg, E, n);
    scan_deg<<<1, 1024, 0, stream>>>(deg, rowptr, n);
    scatter_edges<<<(Et + 255) / 256, 256, 0, stream>>>(ei, rowptr, cursor, csrc, E, n);

    // --- layer 1 ---
    gemm64<<<(n + 63) / 64, 256, 0, stream>>>(x, W1, h1, n, 512);
    alpha1_kernel<<<(n * 8 + 255) / 256, 256, 0, stream>>>(h1, as1, ad1, asrc1, adst1, n);
    agg1_kernel<<<(n + 3) / 4, 256, 0, stream>>>(h1, asrc1, adst1, rowptr, csrc, b1, out1, n);

    // --- layer 2 ---
    gemm64<<<(n + 63) / 64, 256, 0, stream>>>(out1, W2, h2, n, 64);
    alpha2_kernel<<<(n + 3) / 4, 256, 0, stream>>>(h2, as2, ad2, asrc2, adst2, n);
    agg2_kernel<<<(n + 3) / 4, 256, 0, stream>>>(h2, asrc2, adst2, rowptr, csrc, b2, out, n);
}

// Round 4
// 577.026 us; speedup vs baseline: 1.7719x; 1.7719x over previous
//
#include <hip/hip_runtime.h>
#include <hip/hip_bf16.h>
#include <math.h>

// GAT 2-layer: N=50000, IN=512, H=8, C1=8 (H*C1=64), OUT=64, slope=0.2
// R3 resubmit (GPU timeouts R2/R3): CSR-by-dst build, then wave-per-node
// atomic-free segment softmax + aggregation.
//  - no max pass (softmax shift-invariant; logits bounded |t|<~4, exp<=~50,
//    segment sums <= ~1e5 -- no fp32 overflow; equal up to rounding)
//  - lane-parallel exp: each lane owns one edge of a 64-edge chunk, computes
//    all 8 heads' weights, stages into LDS
//  - gather loop: independent iterations, 4-way unrolled, dual accumulators

#define WAVE 64

__device__ inline float wred_sum(float v) {
#pragma unroll
    for (int off = 32; off > 0; off >>= 1) v += __shfl_xor(v, off);
    return v;
}
__device__ inline float wred_max(float v) {
#pragma unroll
    for (int off = 32; off > 0; off >>= 1) v = fmaxf(v, __shfl_xor(v, off));
    return v;
}

// ---------------- CSR build ----------------
__global__ __launch_bounds__(256) void count_deg(const int* __restrict__ ei,
                                                 int* __restrict__ deg, int E, int n) {
    int e = blockIdx.x * 256 + threadIdx.x;
    if (e < E + n) {
        int d = (e < E) ? ei[E + e] : (e - E);   // self-loop dst = node id
        atomicAdd(&deg[d], 1);
    }
}

// single-block exclusive scan over n counters -> rowptr[n+1]
__global__ __launch_bounds__(1024) void scan_deg(const int* __restrict__ deg,
                                                 int* __restrict__ rowptr, int n) {
    __shared__ int part[1024];
    int tid = threadIdx.x;
    int chunk = (n + 1023) >> 10;
    int b = tid * chunk;
    int e = min(b + chunk, n);
    int s = 0;
    for (int i = b; i < e; ++i) s += deg[i];
    part[tid] = s;
    __syncthreads();
    for (int off = 1; off < 1024; off <<= 1) {
        int v = (tid >= off) ? part[tid - off] : 0;
        __syncthreads();
        part[tid] += v;
        __syncthreads();
    }
    int run = (tid == 0) ? 0 : part[tid - 1];
    for (int i = b; i < e; ++i) { rowptr[i] = run; run += deg[i]; }
    if (tid == 1023) rowptr[n] = run;
}

__global__ __launch_bounds__(256) void scatter_edges(const int* __restrict__ ei,
                                                     const int* __restrict__ rowptr,
                                                     int* __restrict__ cursor,
                                                     int* __restrict__ csrc, int E, int n) {
    int e = blockIdx.x * 256 + threadIdx.x;
    if (e < E + n) {
        int s, d;
        if (e < E) { s = ei[e]; d = ei[E + e]; }
        else       { s = e - E; d = s; }
        int pos = rowptr[d] + atomicAdd(&cursor[d], 1);
        csrc[pos] = s;
    }
}

// ---------------- GEMM: O[n][64] = X[n][:K] @ W[:K][64] ----------------
__global__ __launch_bounds__(256) void gemm64(const float* __restrict__ X,
                                              const float* __restrict__ W,
                                              float* __restrict__ O, int nrows, int K) {
    __shared__ float xs[32][68];   // transposed x tile: xs[k][m]
    __shared__ float ws[32][68];   // ws[k][ncol]
    int tid = threadIdx.x;
    int bm = blockIdx.x * 64;
    int tx = tid & 15;             // col quad
    int ty = tid >> 4;             // row quad
    float acc[4][4] = {{0.f}};
    for (int k0 = 0; k0 < K; k0 += 32) {
#pragma unroll
        for (int i = 0; i < 2; ++i) {
            int p = tid + i * 256;       // float4 slot among 512
            int row = p >> 3, k4 = p & 7;
            float4 v = {0.f, 0.f, 0.f, 0.f};
            if (bm + row < nrows)
                v = *(const float4*)(X + (size_t)(bm + row) * K + k0 + k4 * 4);
            xs[k4 * 4 + 0][row] = v.x; xs[k4 * 4 + 1][row] = v.y;
            xs[k4 * 4 + 2][row] = v.z; xs[k4 * 4 + 3][row] = v.w;
        }
#pragma unroll
        for (int i = 0; i < 2; ++i) {
            int p = tid + i * 256;
            int kr = p >> 4, c4 = p & 15;
            float4 v = *(const float4*)(W + (size_t)(k0 + kr) * 64 + c4 * 4);
            ws[kr][c4 * 4 + 0] = v.x; ws[kr][c4 * 4 + 1] = v.y;
            ws[kr][c4 * 4 + 2] = v.z; ws[kr][c4 * 4 + 3] = v.w;
        }
        __syncthreads();
#pragma unroll
        for (int kk = 0; kk < 32; ++kk) {
            float a[4], b[4];
#pragma unroll
            for (int i = 0; i < 4; ++i) a[i] = xs[kk][ty * 4 + i];
#pragma unroll
            for (int j = 0; j < 4; ++j) b[j] = ws[kk][tx * 4 + j];
#pragma unroll
            for (int i = 0; i < 4; ++i)
#pragma unroll
                for (int j = 0; j < 4; ++j) acc[i][j] = fmaf(a[i], b[j], acc[i][j]);
        }
        __syncthreads();
    }
    int row0 = bm + ty * 4;
#pragma unroll
    for (int i = 0; i < 4; ++i) {
        int r = row0 + i;
        if (r < nrows) {
            float4 v = {acc[i][0], acc[i][1], acc[i][2], acc[i][3]};
            *(float4*)(O + (size_t)r * 64 + tx * 4) = v;
        }
    }
}

// ---------------- layer-1 attention coefficients ----------------
__global__ __launch_bounds__(256) void alpha1_kernel(const float* __restrict__ H1,
                                                     const float* __restrict__ as1,
                                                     const float* __restrict__ ad1,
                                                     float* __restrict__ asrc,
                                                     float* __restrict__ adst, int n) {
    int idx = blockIdx.x * 256 + threadIdx.x;
    if (idx >= n * 8) return;
    int h = idx & 7;
    const float* hp = H1 + (size_t)(idx >> 3) * 64 + h * 8;
    float s = 0.f, d = 0.f;
#pragma unroll
    for (int c = 0; c < 8; ++c) {
        float v = hp[c];
        s = fmaf(v, as1[h * 8 + c], s);
        d = fmaf(v, ad1[h * 8 + c], d);
    }
    asrc[idx] = s;
    adst[idx] = d;
}

// ---------------- layer-2 attention coefficients (wave per node) ----------------
__global__ __launch_bounds__(256) void alpha2_kernel(const float* __restrict__ H2,
                                                     const float* __restrict__ as2,
                                                     const float* __restrict__ ad2,
                                                     float* __restrict__ asrc,
                                                     float* __restrict__ adst, int n) {
    int node = blockIdx.x * 4 + (threadIdx.x >> 6);
    int lane = threadIdx.x & 63;
    if (node >= n) return;
    float v = H2[(size_t)node * 64 + lane];
    float s = wred_sum(v * as2[lane]);
    float d = wred_sum(v * ad2[lane]);
    if (lane == 0) { asrc[node] = s; adst[node] = d; }
}

// ---------------- layer-1 aggregation: wave per dst node ----------------
__global__ __launch_bounds__(256) void agg1_kernel(const float* __restrict__ H1,
                                                   const float* __restrict__ asrc,
                                                   const float* __restrict__ adst,
                                                   const int* __restrict__ rowptr,
                                                   const int* __restrict__ csrc,
                                                   const float* __restrict__ b1,
                                                   float* __restrict__ out1, int n) {
    __shared__ float wbuf[4][64][8];   // per-wave: 64 edges x 8 head-weights
    __shared__ int   sbuf[4][64];      // per-wave: 64 src ids
    int wid  = threadIdx.x >> 6;
    int lane = threadIdx.x & 63;
    int node = blockIdx.x * 4 + wid;
    if (node >= n) return;
    int h = lane >> 3;                 // head of this output channel
    int beg = rowptr[node], end = rowptr[node + 1];

    float ad[8];
    *(float4*)&ad[0] = *(const float4*)&adst[(size_t)node * 8];
    *(float4*)&ad[4] = *(const float4*)&adst[(size_t)node * 8 + 4];

    float lsum[8];
#pragma unroll
    for (int i = 0; i < 8; ++i) lsum[i] = 0.f;
    float acc0 = 0.f, acc1 = 0.f;

    for (int c0 = beg; c0 < end; c0 += 64) {
        int e = c0 + lane;
        if (e < end) {
            int s = csrc[e];
            sbuf[wid][lane] = s;
            float a[8], p[8];
            *(float4*)&a[0] = *(const float4*)&asrc[(size_t)s * 8];
            *(float4*)&a[4] = *(const float4*)&asrc[(size_t)s * 8 + 4];
#pragma unroll
            for (int i = 0; i < 8; ++i) {
                float t = a[i] + ad[i];
                t = t > 0.f ? t : 0.2f * t;          // leaky_relu
                p[i] = __expf(t);                    // unnormalized weight
                lsum[i] += p[i];
            }
            *(float4*)&wbuf[wid][lane][0] = *(float4*)&p[0];
            *(float4*)&wbuf[wid][lane][4] = *(float4*)&p[4];
        }
        int cnt = min(64, end - c0);
        // gather-accumulate: independent iterations, 4-way unrolled
        int i = 0;
        for (; i + 3 < cnt; i += 4) {
            int s0 = sbuf[wid][i + 0], s1 = sbuf[wid][i + 1];
            int s2 = sbuf[wid][i + 2], s3 = sbuf[wid][i + 3];
            float w0 = wbuf[wid][i + 0][h], w1 = wbuf[wid][i + 1][h];
            float w2 = wbuf[wid][i + 2][h], w3 = wbuf[wid][i + 3][h];
            float g0 = H1[(size_t)s0 * 64 + lane];
            float g1 = H1[(size_t)s1 * 64 + lane];
            float g2 = H1[(size_t)s2 * 64 + lane];
            float g3 = H1[(size_t)s3 * 64 + lane];
            acc0 = fmaf(g0, w0, acc0);
            acc1 = fmaf(g1, w1, acc1);
            acc0 = fmaf(g2, w2, acc0);
            acc1 = fmaf(g3, w3, acc1);
        }
        for (; i < cnt; ++i) {
            int s   = sbuf[wid][i];
            float w = wbuf[wid][i][h];
            acc0 = fmaf(H1[(size_t)s * 64 + lane], w, acc0);
        }
    }
    float acc = acc0 + acc1;
    // reduce denominators across lanes (each lane holds partials for all heads)
#pragma unroll
    for (int off = 32; off > 0; off >>= 1)
#pragma unroll
        for (int i = 0; i < 8; ++i) lsum[i] += __shfl_xor(lsum[i], off);
    float L = lsum[0];
#pragma unroll
    for (int i = 1; i < 8; ++i) if (h == i) L = lsum[i];   // compile-time idx
    float o = acc / (L + 1e-16f) + b1[lane];
    out1[(size_t)node * 64 + lane] = o > 0.f ? o : expm1f(o);   // ELU
}

// ---------------- layer-2 aggregation + log_softmax ----------------
__global__ __launch_bounds__(256) void agg2_kernel(const float* __restrict__ H2,
                                                   const float* __restrict__ asrc,
                                                   const float* __restrict__ adst,
                                                   const int* __restrict__ rowptr,
                                                   const int* __restrict__ csrc,
                                                   const float* __restrict__ b2,
                                                   float* __restrict__ out, int n) {
    __shared__ float wbuf[4][64];
    __shared__ int   sbuf[4][64];
    int wid  = threadIdx.x >> 6;
    int lane = threadIdx.x & 63;
    int node = blockIdx.x * 4 + wid;
    if (node >= n) return;
    int beg = rowptr[node], end = rowptr[node + 1];
    float ad = adst[node];

    float lsum = 0.f, acc0 = 0.f, acc1 = 0.f;
    for (int c0 = beg; c0 < end; c0 += 64) {
        int e = c0 + lane;
        if (e < end) {
            int s = csrc[e];
            sbuf[wid][lane] = s;
            float t = asrc[s] + ad;
            t = t > 0.f ? t : 0.2f * t;
            float p = __expf(t);
            lsum += p;
            wbuf[wid][lane] = p;
        }
        int cnt = min(64, end - c0);
        int i = 0;
        for (; i + 3 < cnt; i += 4) {
            int s0 = sbuf[wid][i + 0], s1 = sbuf[wid][i + 1];
            int s2 = sbuf[wid][i + 2], s3 = sbuf[wid][i + 3];
            float w0 = wbuf[wid][i + 0], w1 = wbuf[wid][i + 1];
            float w2 = wbuf[wid][i + 2], w3 = wbuf[wid][i + 3];
            float g0 = H2[(size_t)s0 * 64 + lane];
            float g1 = H2[(size_t)s1 * 64 + lane];
            float g2 = H2[(size_t)s2 * 64 + lane];
            float g3 = H2[(size_t)s3 * 64 + lane];
            acc0 = fmaf(g0, w0, acc0);
            acc1 = fmaf(g1, w1, acc1);
            acc0 = fmaf(g2, w2, acc0);
            acc1 = fmaf(g3, w3, acc1);
        }
        for (; i < cnt; ++i) {
            acc0 = fmaf(H2[(size_t)sbuf[wid][i] * 64 + lane], wbuf[wid][i], acc0);
        }
    }
    lsum = wred_sum(lsum);
    float o = (acc0 + acc1) / (lsum + 1e-16f) + b2[lane];
    // log_softmax over 64 channels (one wave = one row)
    float mx = wred_max(o);
    float se = wred_sum(__expf(o - mx));
    out[(size_t)node * 64 + lane] = o - mx - logf(se);
}

extern "C" void kernel_launch(void* const* d_in, const int* in_sizes, int n_in,
                              void* d_out, int out_size, void* d_ws, size_t ws_size,
                              hipStream_t stream) {
    const float* x   = (const float*)d_in[0];
    const int*   ei  = (const int*)d_in[1];
    const float* W1  = (const float*)d_in[2];
    const float* as1 = (const float*)d_in[3];
    const float* ad1 = (const float*)d_in[4];
    const float* b1  = (const float*)d_in[5];
    const float* W2  = (const float*)d_in[6];
    const float* as2 = (const float*)d_in[7];
    const float* ad2 = (const float*)d_in[8];
    const float* b2  = (const float*)d_in[9];
    float* out = (float*)d_out;

    const int n  = in_sizes[0] / 512;   // 50000
    const int E  = in_sizes[1] / 2;     // 1600000
    const int Et = E + n;

    char* w = (char*)d_ws;
    auto alloc = [&](size_t bytes) {
        char* p = w;
        w += (bytes + 255) & ~(size_t)255;
        return p;
    };
    int*   deg    = (int*)alloc((size_t)2 * n * 4);
    int*   cursor = deg + n;
    int*   rowptr = (int*)alloc((size_t)(n + 1) * 4);
    int*   csrc   = (int*)alloc((size_t)Et * 4);
    float* h1     = (float*)alloc((size_t)n * 64 * 4);
    float* out1   = (float*)alloc((size_t)n * 64 * 4);
    float* h2     = (float*)alloc((size_t)n * 64 * 4);
    float* asrc1  = (float*)alloc((size_t)n * 8 * 4);
    float* adst1  = (float*)alloc((size_t)n * 8 * 4);
    float* asrc2  = (float*)alloc((size_t)n * 4);
    float* adst2  = (float*)alloc((size_t)n * 4);

    // --- CSR build ---
    hipMemsetAsync(deg, 0, (size_t)2 * n * 4, stream);
    count_deg<<<(Et + 255) / 256, 256, 0, stream>>>(ei, deg, E, n);
    scan_deg<<<1, 1024, 0, stream>>>(deg, rowptr, n);
    scatter_edges<<<(Et + 255) / 256, 256, 0, stream>>>(ei, rowptr, cursor, csrc, E, n);

    // --- layer 1 ---
    gemm64<<<(n + 63) / 64, 256, 0, stream>>>(x, W1, h1, n, 512);
    alpha1_kernel<<<(n * 8 + 255) / 256, 256, 0, stream>>>(h1, as1, ad1, asrc1, adst1, n);
    agg1_kernel<<<(n + 3) / 4, 256, 0, stream>>>(h1, asrc1, adst1, rowptr, csrc, b1, out1, n);

    // --- layer 2 ---
    gemm64<<<(n + 63) / 64, 256, 0, stream>>>(out1, W2, h2, n, 64);
    alpha2_kernel<<<(n + 3) / 4, 256, 0, stream>>>(h2, as2, ad2, asrc2, adst2, n);
    agg2_kernel<<<(n + 3) / 4, 256, 0, stream>>>(h2, asrc2, adst2, rowptr, csrc, b2, out, n);
}

// Round 6
// 460.053 us; speedup vs baseline: 2.2224x; 1.2543x over previous
//
#include <hip/hip_runtime.h>
#include <hip/hip_bf16.h>
#include <math.h>

// GAT 2-layer: N=50000, IN=512, H=8, C1=8 (H*C1=64), OUT=64, slope=0.2
// R5 resubmit (GPU timeout): CSR build via 2-level counting sort (no global
// atomics):
//   P1 per-block LDS histogram over 391 buckets (dst>>7)
//   P2 single-block 2D prefix -> per-(block,bucket) absolute bases
//   P3 bucketed scatter: open-line working set 25KB/block -> L2 merges writes
//      (fixes the 16x write amplification measured on scatter_edges: 103MB HBM
//       writes for a 6.6MB buffer)
//   P4 per-bucket LDS deg/scan/scatter -> coalesced csrc+rowptr writes
// agg/gemm kernels identical to R3 (isolate the CSR change).

#define WAVE 64
#define NPB_SHIFT 7            // 128 nodes per bucket
#define NB_MAX 512             // static LDS sizing (actual NB = 391)
#define NBLK 128               // blocks for P1/P3 (must match)
#define CAP 6144               // max edges per bucket (mean 4348, sigma ~66)

__device__ inline float wred_sum(float v) {
#pragma unroll
    for (int off = 32; off > 0; off >>= 1) v += __shfl_xor(v, off);
    return v;
}
__device__ inline float wred_max(float v) {
#pragma unroll
    for (int off = 32; off > 0; off >>= 1) v = fmaxf(v, __shfl_xor(v, off));
    return v;
}

// ---------------- P1: per-block bucket histogram ----------------
__global__ __launch_bounds__(256) void bucket_count(const int* __restrict__ ei,
                                                    int* __restrict__ hist,
                                                    int E, int Et, int NB, int epb) {
    __shared__ int lh[NB_MAX];
    for (int t = threadIdx.x; t < NB; t += 256) lh[t] = 0;
    __syncthreads();
    int e0 = blockIdx.x * epb;
    int e1 = min(e0 + epb, Et);
    for (int e = e0 + threadIdx.x; e < e1; e += 256) {
        int d = (e < E) ? ei[E + e] : (e - E);     // self-loop dst = node id
        atomicAdd(&lh[d >> NPB_SHIFT], 1);
    }
    __syncthreads();
    for (int t = threadIdx.x; t < NB; t += 256)
        hist[blockIdx.x * NB + t] = lh[t];
}

// ---------------- P2: totals -> bucket bases -> per-block bases (in place) --
__global__ __launch_bounds__(512) void bucket_scan(int* __restrict__ hist,
                                                   int* __restrict__ bBase,
                                                   int* __restrict__ rowptr,
                                                   int NB, int nblk, int n) {
    __shared__ int tot[NB_MAX];
    for (int b = threadIdx.x; b < NB; b += 512) {
        int s = 0;
        for (int j = 0; j < nblk; ++j) s += hist[j * NB + b];
        tot[b] = s;
    }
    __syncthreads();
    if (threadIdx.x == 0) {
        int run = 0;
        for (int b = 0; b < NB; ++b) { int t = tot[b]; tot[b] = run; bBase[b] = run; run += t; }
        bBase[NB] = run;
        rowptr[n] = run;      // == Et
    }
    __syncthreads();
    for (int b = threadIdx.x; b < NB; b += 512) {
        int run = tot[b];
        for (int j = 0; j < nblk; ++j) { int t = hist[j * NB + b]; hist[j * NB + b] = run; run += t; }
    }
}

// ---------------- P3: bucketed scatter (LDS cursors only) ----------------
__global__ __launch_bounds__(256) void bucket_scatter(const int* __restrict__ ei,
                                                      const int* __restrict__ hist,
                                                      unsigned* __restrict__ region,
                                                      int E, int Et, int NB, int epb) {
    __shared__ int gb[NB_MAX];
    __shared__ int off[NB_MAX];
    for (int t = threadIdx.x; t < NB; t += 256) { gb[t] = hist[blockIdx.x * NB + t]; off[t] = 0; }
    __syncthreads();
    int e0 = blockIdx.x * epb;
    int e1 = min(e0 + epb, Et);
    for (int e = e0 + threadIdx.x; e < e1; e += 256) {
        int s, d;
        if (e < E) { s = ei[e]; d = ei[E + e]; }
        else       { s = d = e - E; }
        int b = d >> NPB_SHIFT;
        int p = gb[b] + atomicAdd(&off[b], 1);
        region[p] = (unsigned)s | ((unsigned)(d & 127) << 16);   // s<65536, dloc<128
    }
}

// ---------------- P4: per-bucket CSR finalize (coalesced writes) ------------
// csrc aliases region: each block reads region[base..base+cnt) fully (into LDS)
// before overwriting the same range; ranges are disjoint across blocks.
__global__ __launch_bounds__(256) void bucket_build(unsigned* __restrict__ region,
                                                    const int* __restrict__ bBase,
                                                    int* __restrict__ rowptr, int n) {
    __shared__ int deg[128], rp[129], cur[128];
    __shared__ unsigned short sb[CAP];
    int b = blockIdx.x;
    int base = bBase[b];
    int cnt  = min(bBase[b + 1] - base, CAP);
    int tid  = threadIdx.x;
    if (tid < 128) { deg[tid] = 0; cur[tid] = 0; }
    __syncthreads();
    for (int i = tid; i < cnt; i += 256)
        atomicAdd(&deg[region[base + i] >> 16], 1);
    __syncthreads();
    if (tid == 0) {
        int run = 0;
        for (int t = 0; t < 128; ++t) { rp[t] = run; run += deg[t]; }
        rp[128] = run;
    }
    __syncthreads();
    int nodeLo = b << NPB_SHIFT;
    if (tid < 128 && nodeLo + tid < n) rowptr[nodeLo + tid] = base + rp[tid];
    for (int i = tid; i < cnt; i += 256) {
        unsigned v = region[base + i];
        int dl = v >> 16;
        int p = rp[dl] + atomicAdd(&cur[dl], 1);
        sb[p] = (unsigned short)(v & 0xFFFFu);
    }
    __syncthreads();
    for (int i = tid; i < cnt; i += 256)
        region[base + i] = (unsigned)sb[i];      // region == csrc from here on
}

// ---------------- GEMM: O[n][64] = X[n][:K] @ W[:K][64] ----------------
__global__ __launch_bounds__(256) void gemm64(const float* __restrict__ X,
                                              const float* __restrict__ W,
                                              float* __restrict__ O, int nrows, int K) {
    __shared__ float xs[32][68];   // transposed x tile: xs[k][m]
    __shared__ float ws[32][68];   // ws[k][ncol]
    int tid = threadIdx.x;
    int bm = blockIdx.x * 64;
    int tx = tid & 15;             // col quad
    int ty = tid >> 4;             // row quad
    float acc[4][4] = {{0.f}};
    for (int k0 = 0; k0 < K; k0 += 32) {
#pragma unroll
        for (int i = 0; i < 2; ++i) {
            int p = tid + i * 256;       // float4 slot among 512
            int row = p >> 3, k4 = p & 7;
            float4 v = {0.f, 0.f, 0.f, 0.f};
            if (bm + row < nrows)
                v = *(const float4*)(X + (size_t)(bm + row) * K + k0 + k4 * 4);
            xs[k4 * 4 + 0][row] = v.x; xs[k4 * 4 + 1][row] = v.y;
            xs[k4 * 4 + 2][row] = v.z; xs[k4 * 4 + 3][row] = v.w;
        }
#pragma unroll
        for (int i = 0; i < 2; ++i) {
            int p = tid + i * 256;
            int kr = p >> 4, c4 = p & 15;
            float4 v = *(const float4*)(W + (size_t)(k0 + kr) * 64 + c4 * 4);
            ws[kr][c4 * 4 + 0] = v.x; ws[kr][c4 * 4 + 1] = v.y;
            ws[kr][c4 * 4 + 2] = v.z; ws[kr][c4 * 4 + 3] = v.w;
        }
        __syncthreads();
#pragma unroll
        for (int kk = 0; kk < 32; ++kk) {
            float a[4], bq[4];
#pragma unroll
            for (int i = 0; i < 4; ++i) a[i] = xs[kk][ty * 4 + i];
#pragma unroll
            for (int j = 0; j < 4; ++j) bq[j] = ws[kk][tx * 4 + j];
#pragma unroll
            for (int i = 0; i < 4; ++i)
#pragma unroll
                for (int j = 0; j < 4; ++j) acc[i][j] = fmaf(a[i], bq[j], acc[i][j]);
        }
        __syncthreads();
    }
    int row0 = bm + ty * 4;
#pragma unroll
    for (int i = 0; i < 4; ++i) {
        int r = row0 + i;
        if (r < nrows) {
            float4 v = {acc[i][0], acc[i][1], acc[i][2], acc[i][3]};
            *(float4*)(O + (size_t)r * 64 + tx * 4) = v;
        }
    }
}

// ---------------- layer-1 attention coefficients ----------------
__global__ __launch_bounds__(256) void alpha1_kernel(const float* __restrict__ H1,
                                                     const float* __restrict__ as1,
                                                     const float* __restrict__ ad1,
                                                     float* __restrict__ asrc,
                                                     float* __restrict__ adst, int n) {
    int idx = blockIdx.x * 256 + threadIdx.x;
    if (idx >= n * 8) return;
    int h = idx & 7;
    const float* hp = H1 + (size_t)(idx >> 3) * 64 + h * 8;
    float s = 0.f, d = 0.f;
#pragma unroll
    for (int c = 0; c < 8; ++c) {
        float v = hp[c];
        s = fmaf(v, as1[h * 8 + c], s);
        d = fmaf(v, ad1[h * 8 + c], d);
    }
    asrc[idx] = s;
    adst[idx] = d;
}

// ---------------- layer-2 attention coefficients (wave per node) ------------
__global__ __launch_bounds__(256) void alpha2_kernel(const float* __restrict__ H2,
                                                     const float* __restrict__ as2,
                                                     const float* __restrict__ ad2,
                                                     float* __restrict__ asrc,
                                                     float* __restrict__ adst, int n) {
    int node = blockIdx.x * 4 + (threadIdx.x >> 6);
    int lane = threadIdx.x & 63;
    if (node >= n) return;
    float v = H2[(size_t)node * 64 + lane];
    float s = wred_sum(v * as2[lane]);
    float d = wred_sum(v * ad2[lane]);
    if (lane == 0) { asrc[node] = s; adst[node] = d; }
}

// ---------------- layer-1 aggregation: wave per dst node ----------------
__global__ __launch_bounds__(256) void agg1_kernel(const float* __restrict__ H1,
                                                   const float* __restrict__ asrc,
                                                   const float* __restrict__ adst,
                                                   const int* __restrict__ rowptr,
                                                   const int* __restrict__ csrc,
                                                   const float* __restrict__ b1,
                                                   float* __restrict__ out1, int n) {
    __shared__ float wbuf[4][64][8];   // per-wave: 64 edges x 8 head-weights
    __shared__ int   sbuf[4][64];      // per-wave: 64 src ids
    int wid  = threadIdx.x >> 6;
    int lane = threadIdx.x & 63;
    int node = blockIdx.x * 4 + wid;
    if (node >= n) return;
    int h = lane >> 3;                 // head of this output channel
    int beg = rowptr[node], end = rowptr[node + 1];

    float ad[8];
    *(float4*)&ad[0] = *(const float4*)&adst[(size_t)node * 8];
    *(float4*)&ad[4] = *(const float4*)&adst[(size_t)node * 8 + 4];

    float lsum[8];
#pragma unroll
    for (int i = 0; i < 8; ++i) lsum[i] = 0.f;
    float acc0 = 0.f, acc1 = 0.f;

    for (int c0 = beg; c0 < end; c0 += 64) {
        int e = c0 + lane;
        if (e < end) {
            int s = csrc[e];
            sbuf[wid][lane] = s;
            float a[8], p[8];
            *(float4*)&a[0] = *(const float4*)&asrc[(size_t)s * 8];
            *(float4*)&a[4] = *(const float4*)&asrc[(size_t)s * 8 + 4];
#pragma unroll
            for (int i = 0; i < 8; ++i) {
                float t = a[i] + ad[i];
                t = t > 0.f ? t : 0.2f * t;          // leaky_relu
                p[i] = __expf(t);                    // unnormalized weight
                lsum[i] += p[i];
            }
            *(float4*)&wbuf[wid][lane][0] = *(float4*)&p[0];
            *(float4*)&wbuf[wid][lane][4] = *(float4*)&p[4];
        }
        int cnt = min(64, end - c0);
        // gather-accumulate: independent iterations, 4-way unrolled
        int i = 0;
        for (; i + 3 < cnt; i += 4) {
            int s0 = sbuf[wid][i + 0], s1 = sbuf[wid][i + 1];
            int s2 = sbuf[wid][i + 2], s3 = sbuf[wid][i + 3];
            float w0 = wbuf[wid][i + 0][h], w1 = wbuf[wid][i + 1][h];
            float w2 = wbuf[wid][i + 2][h], w3 = wbuf[wid][i + 3][h];
            float g0 = H1[(size_t)s0 * 64 + lane];
            float g1 = H1[(size_t)s1 * 64 + lane];
            float g2 = H1[(size_t)s2 * 64 + lane];
            float g3 = H1[(size_t)s3 * 64 + lane];
            acc0 = fmaf(g0, w0, acc0);
            acc1 = fmaf(g1, w1, acc1);
            acc0 = fmaf(g2, w2, acc0);
            acc1 = fmaf(g3, w3, acc1);
        }
        for (; i < cnt; ++i) {
            int s   = sbuf[wid][i];
            float w = wbuf[wid][i][h];
            acc0 = fmaf(H1[(size_t)s * 64 + lane], w, acc0);
        }
    }
    float acc = acc0 + acc1;
#pragma unroll
    for (int off = 32; off > 0; off >>= 1)
#pragma unroll
        for (int i = 0; i < 8; ++i) lsum[i] += __shfl_xor(lsum[i], off);
    float L = lsum[0];
#pragma unroll
    for (int i = 1; i < 8; ++i) if (h == i) L = lsum[i];   // compile-time idx
    float o = acc / (L + 1e-16f) + b1[lane];
    out1[(size_t)node * 64 + lane] = o > 0.f ? o : expm1f(o);   // ELU
}

// ---------------- layer-2 aggregation + log_softmax ----------------
__global__ __launch_bounds__(256) void agg2_kernel(const float* __restrict__ H2,
                                                   const float* __restrict__ asrc,
                                                   const float* __restrict__ adst,
                                                   const int* __restrict__ rowptr,
                                                   const int* __restrict__ csrc,
                                                   const float* __restrict__ b2,
                                                   float* __restrict__ out, int n) {
    __shared__ float wbuf[4][64];
    __shared__ int   sbuf[4][64];
    int wid  = threadIdx.x >> 6;
    int lane = threadIdx.x & 63;
    int node = blockIdx.x * 4 + wid;
    if (node >= n) return;
    int beg = rowptr[node], end = rowptr[node + 1];
    float ad = adst[node];

    float lsum = 0.f, acc0 = 0.f, acc1 = 0.f;
    for (int c0 = beg; c0 < end; c0 += 64) {
        int e = c0 + lane;
        if (e < end) {
            int s = csrc[e];
            sbuf[wid][lane] = s;
            float t = asrc[s] + ad;
            t = t > 0.f ? t : 0.2f * t;
            float p = __expf(t);
            lsum += p;
            wbuf[wid][lane] = p;
        }
        int cnt = min(64, end - c0);
        int i = 0;
        for (; i + 3 < cnt; i += 4) {
            int s0 = sbuf[wid][i + 0], s1 = sbuf[wid][i + 1];
            int s2 = sbuf[wid][i + 2], s3 = sbuf[wid][i + 3];
            float w0 = wbuf[wid][i + 0], w1 = wbuf[wid][i + 1];
            float w2 = wbuf[wid][i + 2], w3 = wbuf[wid][i + 3];
            float g0 = H2[(size_t)s0 * 64 + lane];
            float g1 = H2[(size_t)s1 * 64 + lane];
            float g2 = H2[(size_t)s2 * 64 + lane];
            float g3 = H2[(size_t)s3 * 64 + lane];
            acc0 = fmaf(g0, w0, acc0);
            acc1 = fmaf(g1, w1, acc1);
            acc0 = fmaf(g2, w2, acc0);
            acc1 = fmaf(g3, w3, acc1);
        }
        for (; i < cnt; ++i) {
            acc0 = fmaf(H2[(size_t)sbuf[wid][i] * 64 + lane], wbuf[wid][i], acc0);
        }
    }
    lsum = wred_sum(lsum);
    float o = (acc0 + acc1) / (lsum + 1e-16f) + b2[lane];
    float mx = wred_max(o);
    float se = wred_sum(__expf(o - mx));
    out[(size_t)node * 64 + lane] = o - mx - logf(se);
}

extern "C" void kernel_launch(void* const* d_in, const int* in_sizes, int n_in,
                              void* d_out, int out_size, void* d_ws, size_t ws_size,
                              hipStream_t stream) {
    const float* x   = (const float*)d_in[0];
    const int*   ei  = (const int*)d_in[1];
    const float* W1  = (const float*)d_in[2];
    const float* as1 = (const float*)d_in[3];
    const float* ad1 = (const float*)d_in[4];
    const float* b1  = (const float*)d_in[5];
    const float* W2  = (const float*)d_in[6];
    const float* as2 = (const float*)d_in[7];
    const float* ad2 = (const float*)d_in[8];
    const float* b2  = (const float*)d_in[9];
    float* out = (float*)d_out;

    const int n  = in_sizes[0] / 512;   // 50000
    const int E  = in_sizes[1] / 2;     // 1600000
    const int Et = E + n;
    const int NB  = (n + 127) >> NPB_SHIFT;       // 391 buckets
    const int epb = (Et + NBLK - 1) / NBLK;       // edges per P1/P3 block

    char* w = (char*)d_ws;
    auto alloc = [&](size_t bytes) {
        char* p = w;
        w += (bytes + 255) & ~(size_t)255;
        return p;
    };
    int*      hist   = (int*)alloc((size_t)NBLK * NB * 4);
    int*      bBase  = (int*)alloc((size_t)(NB + 1) * 4);
    unsigned* region = (unsigned*)alloc((size_t)Et * 4);   // becomes csrc
    int*      rowptr = (int*)alloc((size_t)(n + 1) * 4);
    float*    h1     = (float*)alloc((size_t)n * 64 * 4);
    float*    out1   = (float*)alloc((size_t)n * 64 * 4);
    float*    h2     = (float*)alloc((size_t)n * 64 * 4);
    float*    asrc1  = (float*)alloc((size_t)n * 8 * 4);
    float*    adst1  = (float*)alloc((size_t)n * 8 * 4);
    float*    asrc2  = (float*)alloc((size_t)n * 4);
    float*    adst2  = (float*)alloc((size_t)n * 4);
    int*      csrc   = (int*)region;               // alias (see bucket_build)

    // --- CSR build (counting sort, no global atomics) ---
    bucket_count  <<<NBLK, 256, 0, stream>>>(ei, hist, E, Et, NB, epb);
    bucket_scan   <<<1,    512, 0, stream>>>(hist, bBase, rowptr, NB, NBLK, n);
    bucket_scatter<<<NBLK, 256, 0, stream>>>(ei, hist, region, E, Et, NB, epb);
    bucket_build  <<<NB,   256, 0, stream>>>(region, bBase, rowptr, n);

    // --- layer 1 ---
    gemm64<<<(n + 63) / 64, 256, 0, stream>>>(x, W1, h1, n, 512);
    alpha1_kernel<<<(n * 8 + 255) / 256, 256, 0, stream>>>(h1, as1, ad1, asrc1, adst1, n);
    agg1_kernel<<<(n + 3) / 4, 256, 0, stream>>>(h1, asrc1, adst1, rowptr, csrc, b1, out1, n);

    // --- layer 2 ---
    gemm64<<<(n + 63) / 64, 256, 0, stream>>>(out1, W2, h2, n, 64);
    alpha2_kernel<<<(n + 3) / 4, 256, 0, stream>>>(h2, as2, ad2, asrc2, adst2, n);
    agg2_kernel<<<(n + 3) / 4, 256, 0, stream>>>(h2, asrc2, adst2, rowptr, csrc, b2, out, n);
}

// Round 7
// 440.498 us; speedup vs baseline: 2.3211x; 1.0444x over previous
//
#include <hip/hip_runtime.h>
#include <hip/hip_bf16.h>
#include <math.h>

// GAT 2-layer: N=50000, IN=512, H=8, C1=8 (H*C1=64), OUT=64, slope=0.2
// R7: GEMM1 (50000x512 @ 512x64) moved to bf16 MFMA (16x16x32, fp32 accum).
//   - W1 pre-transposed+bf16-converted once (wtrans), L2-resident, reused
//   - 64x64 tile, BK=32, 4 waves x (16 rows x 4 col-frags)
//   - LDS [64][40] bf16 (80B stride): frag ds_read_b128 = 2-way bank alias (free)
//   - frag layout per m97-verified convention (rows from A-operand, cols from B)
// CSR build (counting sort) + agg/alpha/gemm2 identical to R6 (passed, 460us).

#define WAVE 64
#define NPB_SHIFT 7            // 128 nodes per bucket
#define NB_MAX 512             // static LDS sizing (actual NB = 391)
#define NBLK 128               // blocks for P1/P3 (must match)
#define CAP 6144               // max edges per bucket (mean 4348, sigma ~66)

typedef __attribute__((ext_vector_type(8))) short short8;
typedef __attribute__((ext_vector_type(4))) float f32x4;

__device__ inline float wred_sum(float v) {
#pragma unroll
    for (int off = 32; off > 0; off >>= 1) v += __shfl_xor(v, off);
    return v;
}
__device__ inline float wred_max(float v) {
#pragma unroll
    for (int off = 32; off > 0; off >>= 1) v = fmaxf(v, __shfl_xor(v, off));
    return v;
}
__device__ inline unsigned short f2bf(float f) {   // round-to-nearest-even
    unsigned u = __float_as_uint(f);
    u += 0x7FFFu + ((u >> 16) & 1u);
    return (unsigned short)(u >> 16);
}

// ---------------- P1: per-block bucket histogram ----------------
__global__ __launch_bounds__(256) void bucket_count(const int* __restrict__ ei,
                                                    int* __restrict__ hist,
                                                    int E, int Et, int NB, int epb) {
    __shared__ int lh[NB_MAX];
    for (int t = threadIdx.x; t < NB; t += 256) lh[t] = 0;
    __syncthreads();
    int e0 = blockIdx.x * epb;
    int e1 = min(e0 + epb, Et);
    for (int e = e0 + threadIdx.x; e < e1; e += 256) {
        int d = (e < E) ? ei[E + e] : (e - E);     // self-loop dst = node id
        atomicAdd(&lh[d >> NPB_SHIFT], 1);
    }
    __syncthreads();
    for (int t = threadIdx.x; t < NB; t += 256)
        hist[blockIdx.x * NB + t] = lh[t];
}

// ---------------- P2: totals -> bucket bases -> per-block bases (in place) --
__global__ __launch_bounds__(512) void bucket_scan(int* __restrict__ hist,
                                                   int* __restrict__ bBase,
                                                   int* __restrict__ rowptr,
                                                   int NB, int nblk, int n) {
    __shared__ int tot[NB_MAX];
    for (int b = threadIdx.x; b < NB; b += 512) {
        int s = 0;
        for (int j = 0; j < nblk; ++j) s += hist[j * NB + b];
        tot[b] = s;
    }
    __syncthreads();
    if (threadIdx.x == 0) {
        int run = 0;
        for (int b = 0; b < NB; ++b) { int t = tot[b]; tot[b] = run; bBase[b] = run; run += t; }
        bBase[NB] = run;
        rowptr[n] = run;      // == Et
    }
    __syncthreads();
    for (int b = threadIdx.x; b < NB; b += 512) {
        int run = tot[b];
        for (int j = 0; j < nblk; ++j) { int t = hist[j * NB + b]; hist[j * NB + b] = run; run += t; }
    }
}

// ---------------- P3: bucketed scatter (LDS cursors only) ----------------
__global__ __launch_bounds__(256) void bucket_scatter(const int* __restrict__ ei,
                                                      const int* __restrict__ hist,
                                                      unsigned* __restrict__ region,
                                                      int E, int Et, int NB, int epb) {
    __shared__ int gb[NB_MAX];
    __shared__ int off[NB_MAX];
    for (int t = threadIdx.x; t < NB; t += 256) { gb[t] = hist[blockIdx.x * NB + t]; off[t] = 0; }
    __syncthreads();
    int e0 = blockIdx.x * epb;
    int e1 = min(e0 + epb, Et);
    for (int e = e0 + threadIdx.x; e < e1; e += 256) {
        int s, d;
        if (e < E) { s = ei[e]; d = ei[E + e]; }
        else       { s = d = e - E; }
        int b = d >> NPB_SHIFT;
        int p = gb[b] + atomicAdd(&off[b], 1);
        region[p] = (unsigned)s | ((unsigned)(d & 127) << 16);   // s<65536, dloc<128
    }
}

// ---------------- P4: per-bucket CSR finalize (coalesced writes) ------------
__global__ __launch_bounds__(256) void bucket_build(unsigned* __restrict__ region,
                                                    const int* __restrict__ bBase,
                                                    int* __restrict__ rowptr, int n) {
    __shared__ int deg[128], rp[129], cur[128];
    __shared__ unsigned short sb[CAP];
    int b = blockIdx.x;
    int base = bBase[b];
    int cnt  = min(bBase[b + 1] - base, CAP);
    int tid  = threadIdx.x;
    if (tid < 128) { deg[tid] = 0; cur[tid] = 0; }
    __syncthreads();
    for (int i = tid; i < cnt; i += 256)
        atomicAdd(&deg[region[base + i] >> 16], 1);
    __syncthreads();
    if (tid == 0) {
        int run = 0;
        for (int t = 0; t < 128; ++t) { rp[t] = run; run += deg[t]; }
        rp[128] = run;
    }
    __syncthreads();
    int nodeLo = b << NPB_SHIFT;
    if (tid < 128 && nodeLo + tid < n) rowptr[nodeLo + tid] = base + rp[tid];
    for (int i = tid; i < cnt; i += 256) {
        unsigned v = region[base + i];
        int dl = v >> 16;
        int p = rp[dl] + atomicAdd(&cur[dl], 1);
        sb[p] = (unsigned short)(v & 0xFFFFu);
    }
    __syncthreads();
    for (int i = tid; i < cnt; i += 256)
        region[base + i] = (unsigned)sb[i];      // region == csrc from here on
}

// ---------------- W1 pre-transpose + bf16 convert: wtg[c][k] ----------------
__global__ __launch_bounds__(256) void wtrans_kernel(const float* __restrict__ W,
                                                     unsigned short* __restrict__ wtg) {
    int idx = blockIdx.x * 256 + threadIdx.x;       // 64*512
    if (idx >= 64 * 512) return;
    int c = idx >> 9, k = idx & 511;
    wtg[c * 512 + k] = f2bf(W[k * 64 + c]);
}

// ---------------- GEMM1: h1[n][64] = x[n][512] @ W1 via bf16 MFMA ----------
__global__ __launch_bounds__(256) void gemm1_mfma(const float* __restrict__ X,
                                                  const unsigned short* __restrict__ wtg,
                                                  float* __restrict__ O, int nrows) {
    __shared__ unsigned short xs[64][40];   // 80B row stride: b128 frag = 2-way bank (free)
    __shared__ unsigned short wt[64][40];
    int tid  = threadIdx.x;
    int wid  = tid >> 6;
    int lane = tid & 63;
    int lr   = lane & 15;      // fragment row/col index
    int lg   = lane >> 4;      // k-group (0..3)
    int bm   = blockIdx.x * 64;

    f32x4 acc[4];
#pragma unroll
    for (int i = 0; i < 4; ++i) acc[i] = (f32x4){0.f, 0.f, 0.f, 0.f};

    for (int k0 = 0; k0 < 512; k0 += 32) {
        // stage x tile 64x32 fp32 -> bf16 (512 float4 slots, 2/thread)
#pragma unroll
        for (int i = 0; i < 2; ++i) {
            int p = tid + i * 256;
            int row = p >> 3, c4 = p & 7;
            float4 v = {0.f, 0.f, 0.f, 0.f};
            if (bm + row < nrows)
                v = *(const float4*)(X + (size_t)(bm + row) * 512 + k0 + c4 * 4);
            unsigned short* dst = &xs[row][c4 * 4];
            dst[0] = f2bf(v.x); dst[1] = f2bf(v.y); dst[2] = f2bf(v.z); dst[3] = f2bf(v.w);
        }
        // stage W^T tile 64x32 bf16 (256 chunks of 8 shorts, 1/thread)
        {
            int c = tid >> 2, kq = tid & 3;
            *(short8*)&wt[c][kq * 8] = *(const short8*)&wtg[c * 512 + k0 + kq * 8];
        }
        __syncthreads();
        short8 af = *(short8*)&xs[wid * 16 + lr][lg * 8];
#pragma unroll
        for (int cb = 0; cb < 4; ++cb) {
            short8 bfb = *(short8*)&wt[cb * 16 + lr][lg * 8];
            acc[cb] = __builtin_amdgcn_mfma_f32_16x16x32_bf16(af, bfb, acc[cb], 0, 0, 0);
        }
        __syncthreads();
    }
    // C: row = bm + wid*16 + lg*4 + r (A side), col = cb*16 + lr (B side)
#pragma unroll
    for (int cb = 0; cb < 4; ++cb)
#pragma unroll
        for (int r = 0; r < 4; ++r) {
            int m = bm + wid * 16 + lg * 4 + r;
            if (m < nrows) O[(size_t)m * 64 + cb * 16 + lr] = acc[cb][r];
        }
}

// ---------------- GEMM: O[n][64] = X[n][:K] @ W[:K][64] (fp32, layer 2) -----
__global__ __launch_bounds__(256) void gemm64(const float* __restrict__ X,
                                              const float* __restrict__ W,
                                              float* __restrict__ O, int nrows, int K) {
    __shared__ float xs[32][68];   // transposed x tile: xs[k][m]
    __shared__ float ws[32][68];   // ws[k][ncol]
    int tid = threadIdx.x;
    int bm = blockIdx.x * 64;
    int tx = tid & 15;             // col quad
    int ty = tid >> 4;             // row quad
    float acc[4][4] = {{0.f}};
    for (int k0 = 0; k0 < K; k0 += 32) {
#pragma unroll
        for (int i = 0; i < 2; ++i) {
            int p = tid + i * 256;       // float4 slot among 512
            int row = p >> 3, k4 = p & 7;
            float4 v = {0.f, 0.f, 0.f, 0.f};
            if (bm + row < nrows)
                v = *(const float4*)(X + (size_t)(bm + row) * K + k0 + k4 * 4);
            xs[k4 * 4 + 0][row] = v.x; xs[k4 * 4 + 1][row] = v.y;
            xs[k4 * 4 + 2][row] = v.z; xs[k4 * 4 + 3][row] = v.w;
        }
#pragma unroll
        for (int i = 0; i < 2; ++i) {
            int p = tid + i * 256;
            int kr = p >> 4, c4 = p & 15;
            float4 v = *(const float4*)(W + (size_t)(k0 + kr) * 64 + c4 * 4);
            ws[kr][c4 * 4 + 0] = v.x; ws[kr][c4 * 4 + 1] = v.y;
            ws[kr][c4 * 4 + 2] = v.z; ws[kr][c4 * 4 + 3] = v.w;
        }
        __syncthreads();
#pragma unroll
        for (int kk = 0; kk < 32; ++kk) {
            float a[4], bq[4];
#pragma unroll
            for (int i = 0; i < 4; ++i) a[i] = xs[kk][ty * 4 + i];
#pragma unroll
            for (int j = 0; j < 4; ++j) bq[j] = ws[kk][tx * 4 + j];
#pragma unroll
            for (int i = 0; i < 4; ++i)
#pragma unroll
                for (int j = 0; j < 4; ++j) acc[i][j] = fmaf(a[i], bq[j], acc[i][j]);
        }
        __syncthreads();
    }
    int row0 = bm + ty * 4;
#pragma unroll
    for (int i = 0; i < 4; ++i) {
        int r = row0 + i;
        if (r < nrows) {
            float4 v = {acc[i][0], acc[i][1], acc[i][2], acc[i][3]};
            *(float4*)(O + (size_t)r * 64 + tx * 4) = v;
        }
    }
}

// ---------------- layer-1 attention coefficients ----------------
__global__ __launch_bounds__(256) void alpha1_kernel(const float* __restrict__ H1,
                                                     const float* __restrict__ as1,
                                                     const float* __restrict__ ad1,
                                                     float* __restrict__ asrc,
                                                     float* __restrict__ adst, int n) {
    int idx = blockIdx.x * 256 + threadIdx.x;
    if (idx >= n * 8) return;
    int h = idx & 7;
    const float* hp = H1 + (size_t)(idx >> 3) * 64 + h * 8;
    float s = 0.f, d = 0.f;
#pragma unroll
    for (int c = 0; c < 8; ++c) {
        float v = hp[c];
        s = fmaf(v, as1[h * 8 + c], s);
        d = fmaf(v, ad1[h * 8 + c], d);
    }
    asrc[idx] = s;
    adst[idx] = d;
}

// ---------------- layer-2 attention coefficients (wave per node) ------------
__global__ __launch_bounds__(256) void alpha2_kernel(const float* __restrict__ H2,
                                                     const float* __restrict__ as2,
                                                     const float* __restrict__ ad2,
                                                     float* __restrict__ asrc,
                                                     float* __restrict__ adst, int n) {
    int node = blockIdx.x * 4 + (threadIdx.x >> 6);
    int lane = threadIdx.x & 63;
    if (node >= n) return;
    float v = H2[(size_t)node * 64 + lane];
    float s = wred_sum(v * as2[lane]);
    float d = wred_sum(v * ad2[lane]);
    if (lane == 0) { asrc[node] = s; adst[node] = d; }
}

// ---------------- layer-1 aggregation: wave per dst node ----------------
__global__ __launch_bounds__(256) void agg1_kernel(const float* __restrict__ H1,
                                                   const float* __restrict__ asrc,
                                                   const float* __restrict__ adst,
                                                   const int* __restrict__ rowptr,
                                                   const int* __restrict__ csrc,
                                                   const float* __restrict__ b1,
                                                   float* __restrict__ out1, int n) {
    __shared__ float wbuf[4][64][8];   // per-wave: 64 edges x 8 head-weights
    __shared__ int   sbuf[4][64];      // per-wave: 64 src ids
    int wid  = threadIdx.x >> 6;
    int lane = threadIdx.x & 63;
    int node = blockIdx.x * 4 + wid;
    if (node >= n) return;
    int h = lane >> 3;                 // head of this output channel
    int beg = rowptr[node], end = rowptr[node + 1];

    float ad[8];
    *(float4*)&ad[0] = *(const float4*)&adst[(size_t)node * 8];
    *(float4*)&ad[4] = *(const float4*)&adst[(size_t)node * 8 + 4];

    float lsum[8];
#pragma unroll
    for (int i = 0; i < 8; ++i) lsum[i] = 0.f;
    float acc0 = 0.f, acc1 = 0.f;

    for (int c0 = beg; c0 < end; c0 += 64) {
        int e = c0 + lane;
        if (e < end) {
            int s = csrc[e];
            sbuf[wid][lane] = s;
            float a[8], p[8];
            *(float4*)&a[0] = *(const float4*)&asrc[(size_t)s * 8];
            *(float4*)&a[4] = *(const float4*)&asrc[(size_t)s * 8 + 4];
#pragma unroll
            for (int i = 0; i < 8; ++i) {
                float t = a[i] + ad[i];
                t = t > 0.f ? t : 0.2f * t;          // leaky_relu
                p[i] = __expf(t);                    // unnormalized weight
                lsum[i] += p[i];
            }
            *(float4*)&wbuf[wid][lane][0] = *(float4*)&p[0];
            *(float4*)&wbuf[wid][lane][4] = *(float4*)&p[4];
        }
        int cnt = min(64, end - c0);
        // gather-accumulate: independent iterations, 4-way unrolled
        int i = 0;
        for (; i + 3 < cnt; i += 4) {
            int s0 = sbuf[wid][i + 0], s1 = sbuf[wid][i + 1];
            int s2 = sbuf[wid][i + 2], s3 = sbuf[wid][i + 3];
            float w0 = wbuf[wid][i + 0][h], w1 = wbuf[wid][i + 1][h];
            float w2 = wbuf[wid][i + 2][h], w3 = wbuf[wid][i + 3][h];
            float g0 = H1[(size_t)s0 * 64 + lane];
            float g1 = H1[(size_t)s1 * 64 + lane];
            float g2 = H1[(size_t)s2 * 64 + lane];
            float g3 = H1[(size_t)s3 * 64 + lane];
            acc0 = fmaf(g0, w0, acc0);
            acc1 = fmaf(g1, w1, acc1);
            acc0 = fmaf(g2, w2, acc0);
            acc1 = fmaf(g3, w3, acc1);
        }
        for (; i < cnt; ++i) {
            int s   = sbuf[wid][i];
            float w = wbuf[wid][i][h];
            acc0 = fmaf(H1[(size_t)s * 64 + lane], w, acc0);
        }
    }
    float acc = acc0 + acc1;
#pragma unroll
    for (int off = 32; off > 0; off >>= 1)
#pragma unroll
        for (int i = 0; i < 8; ++i) lsum[i] += __shfl_xor(lsum[i], off);
    float L = lsum[0];
#pragma unroll
    for (int i = 1; i < 8; ++i) if (h == i) L = lsum[i];   // compile-time idx
    float o = acc / (L + 1e-16f) + b1[lane];
    out1[(size_t)node * 64 + lane] = o > 0.f ? o : expm1f(o);   // ELU
}

// ---------------- layer-2 aggregation + log_softmax ----------------
__global__ __launch_bounds__(256) void agg2_kernel(const float* __restrict__ H2,
                                                   const float* __restrict__ asrc,
                                                   const float* __restrict__ adst,
                                                   const int* __restrict__ rowptr,
                                                   const int* __restrict__ csrc,
                                                   const float* __restrict__ b2,
                                                   float* __restrict__ out, int n) {
    __shared__ float wbuf[4][64];
    __shared__ int   sbuf[4][64];
    int wid  = threadIdx.x >> 6;
    int lane = threadIdx.x & 63;
    int node = blockIdx.x * 4 + wid;
    if (node >= n) return;
    int beg = rowptr[node], end = rowptr[node + 1];
    float ad = adst[node];

    float lsum = 0.f, acc0 = 0.f, acc1 = 0.f;
    for (int c0 = beg; c0 < end; c0 += 64) {
        int e = c0 + lane;
        if (e < end) {
            int s = csrc[e];
            sbuf[wid][lane] = s;
            float t = asrc[s] + ad;
            t = t > 0.f ? t : 0.2f * t;
            float p = __expf(t);
            lsum += p;
            wbuf[wid][lane] = p;
        }
        int cnt = min(64, end - c0);
        int i = 0;
        for (; i + 3 < cnt; i += 4) {
            int s0 = sbuf[wid][i + 0], s1 = sbuf[wid][i + 1];
            int s2 = sbuf[wid][i + 2], s3 = sbuf[wid][i + 3];
            float w0 = wbuf[wid][i + 0], w1 = wbuf[wid][i + 1];
            float w2 = wbuf[wid][i + 2], w3 = wbuf[wid][i + 3];
            float g0 = H2[(size_t)s0 * 64 + lane];
            float g1 = H2[(size_t)s1 * 64 + lane];
            float g2 = H2[(size_t)s2 * 64 + lane];
            float g3 = H2[(size_t)s3 * 64 + lane];
            acc0 = fmaf(g0, w0, acc0);
            acc1 = fmaf(g1, w1, acc1);
            acc0 = fmaf(g2, w2, acc0);
            acc1 = fmaf(g3, w3, acc1);
        }
        for (; i < cnt; ++i) {
            acc0 = fmaf(H2[(size_t)sbuf[wid][i] * 64 + lane], wbuf[wid][i], acc0);
        }
    }
    lsum = wred_sum(lsum);
    float o = (acc0 + acc1) / (lsum + 1e-16f) + b2[lane];
    float mx = wred_max(o);
    float se = wred_sum(__expf(o - mx));
    out[(size_t)node * 64 + lane] = o - mx - logf(se);
}

extern "C" void kernel_launch(void* const* d_in, const int* in_sizes, int n_in,
                              void* d_out, int out_size, void* d_ws, size_t ws_size,
                              hipStream_t stream) {
    const float* x   = (const float*)d_in[0];
    const int*   ei  = (const int*)d_in[1];
    const float* W1  = (const float*)d_in[2];
    const float* as1 = (const float*)d_in[3];
    const float* ad1 = (const float*)d_in[4];
    const float* b1  = (const float*)d_in[5];
    const float* W2  = (const float*)d_in[6];
    const float* as2 = (const float*)d_in[7];
    const float* ad2 = (const float*)d_in[8];
    const float* b2  = (const float*)d_in[9];
    float* out = (float*)d_out;

    const int n  = in_sizes[0] / 512;   // 50000
    const int E  = in_sizes[1] / 2;     // 1600000
    const int Et = E + n;
    const int NB  = (n + 127) >> NPB_SHIFT;       // 391 buckets
    const int epb = (Et + NBLK - 1) / NBLK;       // edges per P1/P3 block

    char* w = (char*)d_ws;
    auto alloc = [&](size_t bytes) {
        char* p = w;
        w += (bytes + 255) & ~(size_t)255;
        return p;
    };
    int*            hist   = (int*)alloc((size_t)NBLK * NB * 4);
    int*            bBase  = (int*)alloc((size_t)(NB + 1) * 4);
    unsigned*       region = (unsigned*)alloc((size_t)Et * 4);   // becomes csrc
    int*            rowptr = (int*)alloc((size_t)(n + 1) * 4);
    float*          h1     = (float*)alloc((size_t)n * 64 * 4);
    float*          out1   = (float*)alloc((size_t)n * 64 * 4);
    float*          h2     = (float*)alloc((size_t)n * 64 * 4);
    float*          asrc1  = (float*)alloc((size_t)n * 8 * 4);
    float*          adst1  = (float*)alloc((size_t)n * 8 * 4);
    float*          asrc2  = (float*)alloc((size_t)n * 4);
    float*          adst2  = (float*)alloc((size_t)n * 4);
    unsigned short* wtg    = (unsigned short*)alloc((size_t)64 * 512 * 2);
    int*            csrc   = (int*)region;         // alias (see bucket_build)

    // --- CSR build (counting sort, no global atomics) ---
    bucket_count  <<<NBLK, 256, 0, stream>>>(ei, hist, E, Et, NB, epb);
    bucket_scan   <<<1,    512, 0, stream>>>(hist, bBase, rowptr, NB, NBLK, n);
    bucket_scatter<<<NBLK, 256, 0, stream>>>(ei, hist, region, E, Et, NB, epb);
    bucket_build  <<<NB,   256, 0, stream>>>(region, bBase, rowptr, n);

    // --- layer 1 ---
    wtrans_kernel<<<(64 * 512 + 255) / 256, 256, 0, stream>>>(W1, wtg);
    gemm1_mfma<<<(n + 63) / 64, 256, 0, stream>>>(x, wtg, h1, n);
    alpha1_kernel<<<(n * 8 + 255) / 256, 256, 0, stream>>>(h1, as1, ad1, asrc1, adst1, n);
    agg1_kernel<<<(n + 3) / 4, 256, 0, stream>>>(h1, asrc1, adst1, rowptr, csrc, b1, out1, n);

    // --- layer 2 ---
    gemm64<<<(n + 63) / 64, 256, 0, stream>>>(out1, W2, h2, n, 64);
    alpha2_kernel<<<(n + 3) / 4, 256, 0, stream>>>(h2, as2, ad2, asrc2, adst2, n);
    agg2_kernel<<<(n + 3) / 4, 256, 0, stream>>>(h2, asrc2, adst2, rowptr, csrc, b2, out, n);
}

// Round 11
// 415.135 us; speedup vs baseline: 2.4629x; 1.0611x over previous
//
#include <hip/hip_runtime.h>
#include <hip/hip_bf16.h>
#include <math.h>

// GAT 2-layer: N=50000, IN=512, H=8, C1=8 (H*C1=64), OUT=64, slope=0.2
// R8 resubmit x4 (GPU timeouts): bf16 storage for every GATHERED tensor (h1,
// out1, h2, asrc1) -> halves the 422MB/layer edge-gather traffic that R7's
// counters showed as the bottleneck (agg1: 201MB FETCH, 41% HBM).
// GEMM2 -> bf16 MFMA. All accumulation/softmax/log_softmax stay fp32.
// CSR counting-sort build identical to R6/R7 (passed).

#define WAVE 64
#define NPB_SHIFT 7            // 128 nodes per bucket
#define NB_MAX 512             // static LDS sizing (actual NB = 391)
#define NBLK 128               // blocks for P1/P3 (must match)
#define CAP 6144               // max edges per bucket (mean 4348, sigma ~66)

typedef __attribute__((ext_vector_type(8))) short short8;
typedef __attribute__((ext_vector_type(4))) float f32x4;

__device__ inline float wred_sum(float v) {
#pragma unroll
    for (int off = 32; off > 0; off >>= 1) v += __shfl_xor(v, off);
    return v;
}
__device__ inline float wred_max(float v) {
#pragma unroll
    for (int off = 32; off > 0; off >>= 1) v = fmaxf(v, __shfl_xor(v, off));
    return v;
}
__device__ inline unsigned short f2bf(float f) {   // round-to-nearest-even
    unsigned u = __float_as_uint(f);
    u += 0x7FFFu + ((u >> 16) & 1u);
    return (unsigned short)(u >> 16);
}
__device__ inline float bf2f(unsigned short u) {
    return __uint_as_float((unsigned)u << 16);
}

// ---------------- P1: per-block bucket histogram ----------------
__global__ __launch_bounds__(256) void bucket_count(const int* __restrict__ ei,
                                                    int* __restrict__ hist,
                                                    int E, int Et, int NB, int epb) {
    __shared__ int lh[NB_MAX];
    for (int t = threadIdx.x; t < NB; t += 256) lh[t] = 0;
    __syncthreads();
    int e0 = blockIdx.x * epb;
    int e1 = min(e0 + epb, Et);
    for (int e = e0 + threadIdx.x; e < e1; e += 256) {
        int d = (e < E) ? ei[E + e] : (e - E);     // self-loop dst = node id
        atomicAdd(&lh[d >> NPB_SHIFT], 1);
    }
    __syncthreads();
    for (int t = threadIdx.x; t < NB; t += 256)
        hist[blockIdx.x * NB + t] = lh[t];
}

// ---------------- P2: totals -> bucket bases -> per-block bases (in place) --
__global__ __launch_bounds__(512) void bucket_scan(int* __restrict__ hist,
                                                   int* __restrict__ bBase,
                                                   int* __restrict__ rowptr,
                                                   int NB, int nblk, int n) {
    __shared__ int tot[NB_MAX];
    for (int b = threadIdx.x; b < NB; b += 512) {
        int s = 0;
        for (int j = 0; j < nblk; ++j) s += hist[j * NB + b];
        tot[b] = s;
    }
    __syncthreads();
    if (threadIdx.x == 0) {
        int run = 0;
        for (int b = 0; b < NB; ++b) { int t = tot[b]; tot[b] = run; bBase[b] = run; run += t; }
        bBase[NB] = run;
        rowptr[n] = run;      // == Et
    }
    __syncthreads();
    for (int b = threadIdx.x; b < NB; b += 512) {
        int run = tot[b];
        for (int j = 0; j < nblk; ++j) { int t = hist[j * NB + b]; hist[j * NB + b] = run; run += t; }
    }
}

// ---------------- P3: bucketed scatter (LDS cursors only) ----------------
__global__ __launch_bounds__(256) void bucket_scatter(const int* __restrict__ ei,
                                                      const int* __restrict__ hist,
                                                      unsigned* __restrict__ region,
                                                      int E, int Et, int NB, int epb) {
    __shared__ int gb[NB_MAX];
    __shared__ int off[NB_MAX];
    for (int t = threadIdx.x; t < NB; t += 256) { gb[t] = hist[blockIdx.x * NB + t]; off[t] = 0; }
    __syncthreads();
    int e0 = blockIdx.x * epb;
    int e1 = min(e0 + epb, Et);
    for (int e = e0 + threadIdx.x; e < e1; e += 256) {
        int s, d;
        if (e < E) { s = ei[e]; d = ei[E + e]; }
        else       { s = d = e - E; }
        int b = d >> NPB_SHIFT;
        int p = gb[b] + atomicAdd(&off[b], 1);
        region[p] = (unsigned)s | ((unsigned)(d & 127) << 16);   // s<65536, dloc<128
    }
}

// ---------------- P4: per-bucket CSR finalize (coalesced writes) ------------
__global__ __launch_bounds__(256) void bucket_build(unsigned* __restrict__ region,
                                                    const int* __restrict__ bBase,
                                                    int* __restrict__ rowptr, int n) {
    __shared__ int deg[128], rp[129], cur[128];
    __shared__ unsigned short sb[CAP];
    int b = blockIdx.x;
    int base = bBase[b];
    int cnt  = min(bBase[b + 1] - base, CAP);
    int tid  = threadIdx.x;
    if (tid < 128) { deg[tid] = 0; cur[tid] = 0; }
    __syncthreads();
    for (int i = tid; i < cnt; i += 256)
        atomicAdd(&deg[region[base + i] >> 16], 1);
    __syncthreads();
    if (tid == 0) {
        int run = 0;
        for (int t = 0; t < 128; ++t) { rp[t] = run; run += deg[t]; }
        rp[128] = run;
    }
    __syncthreads();
    int nodeLo = b << NPB_SHIFT;
    if (tid < 128 && nodeLo + tid < n) rowptr[nodeLo + tid] = base + rp[tid];
    for (int i = tid; i < cnt; i += 256) {
        unsigned v = region[base + i];
        int dl = v >> 16;
        int p = rp[dl] + atomicAdd(&cur[dl], 1);
        sb[p] = (unsigned short)(v & 0xFFFFu);
    }
    __syncthreads();
    for (int i = tid; i < cnt; i += 256)
        region[base + i] = (unsigned)sb[i];      // region == csrc from here on
}

// ---------------- W1 pre-transpose + bf16: wtg[c][k], c<64, k<512 -----------
__global__ __launch_bounds__(256) void wtrans_kernel(const float* __restrict__ W,
                                                     unsigned short* __restrict__ wtg) {
    int idx = blockIdx.x * 256 + threadIdx.x;       // 64*512
    if (idx >= 64 * 512) return;
    int c = idx >> 9, k = idx & 511;
    wtg[c * 512 + k] = f2bf(W[k * 64 + c]);
}

// ---------------- W2 pre-transpose + bf16: wt2[c][k], c<64, k<64 ------------
__global__ __launch_bounds__(256) void wtrans2_kernel(const float* __restrict__ W,
                                                      unsigned short* __restrict__ wt2) {
    int idx = blockIdx.x * 256 + threadIdx.x;       // 64*64
    if (idx >= 64 * 64) return;
    int c = idx >> 6, k = idx & 63;
    wt2[c * 64 + k] = f2bf(W[k * 64 + c]);
}

// ---------------- GEMM1: h1b[n][64] = bf16(x[n][512] @ W1), MFMA -----------
__global__ __launch_bounds__(256) void gemm1_mfma(const float* __restrict__ X,
                                                  const unsigned short* __restrict__ wtg,
                                                  unsigned short* __restrict__ O, int nrows) {
    __shared__ unsigned short xs[64][40];   // 80B row stride: b128 frag = 2-way bank (free)
    __shared__ unsigned short wt[64][40];
    int tid  = threadIdx.x;
    int wid  = tid >> 6;
    int lane = tid & 63;
    int lr   = lane & 15;      // fragment row/col index
    int lg   = lane >> 4;      // k-group (0..3)
    int bm   = blockIdx.x * 64;

    f32x4 acc[4];
#pragma unroll
    for (int i = 0; i < 4; ++i) acc[i] = (f32x4){0.f, 0.f, 0.f, 0.f};

    for (int k0 = 0; k0 < 512; k0 += 32) {
#pragma unroll
        for (int i = 0; i < 2; ++i) {
            int p = tid + i * 256;
            int row = p >> 3, c4 = p & 7;
            float4 v = {0.f, 0.f, 0.f, 0.f};
            if (bm + row < nrows)
                v = *(const float4*)(X + (size_t)(bm + row) * 512 + k0 + c4 * 4);
            unsigned short* dst = &xs[row][c4 * 4];
            dst[0] = f2bf(v.x); dst[1] = f2bf(v.y); dst[2] = f2bf(v.z); dst[3] = f2bf(v.w);
        }
        {
            int c = tid >> 2, kq = tid & 3;
            *(short8*)&wt[c][kq * 8] = *(const short8*)&wtg[c * 512 + k0 + kq * 8];
        }
        __syncthreads();
        short8 af = *(short8*)&xs[wid * 16 + lr][lg * 8];
#pragma unroll
        for (int cb = 0; cb < 4; ++cb) {
            short8 bfb = *(short8*)&wt[cb * 16 + lr][lg * 8];
            acc[cb] = __builtin_amdgcn_mfma_f32_16x16x32_bf16(af, bfb, acc[cb], 0, 0, 0);
        }
        __syncthreads();
    }
#pragma unroll
    for (int cb = 0; cb < 4; ++cb)
#pragma unroll
        for (int r = 0; r < 4; ++r) {
            int m = bm + wid * 16 + lg * 4 + r;
            if (m < nrows) O[(size_t)m * 64 + cb * 16 + lr] = f2bf(acc[cb][r]);
        }
}

// ---------------- GEMM2: h2b[n][64] = bf16(out1b[n][64] @ W2), MFMA --------
__global__ __launch_bounds__(256) void gemm2_mfma(const unsigned short* __restrict__ X,
                                                  const unsigned short* __restrict__ wt2,
                                                  unsigned short* __restrict__ O, int nrows) {
    __shared__ unsigned short xs[64][40];
    __shared__ unsigned short wt[64][40];
    int tid  = threadIdx.x;
    int wid  = tid >> 6;
    int lane = tid & 63;
    int lr   = lane & 15;
    int lg   = lane >> 4;
    int bm   = blockIdx.x * 64;

    f32x4 acc[4];
#pragma unroll
    for (int i = 0; i < 4; ++i) acc[i] = (f32x4){0.f, 0.f, 0.f, 0.f};

#pragma unroll
    for (int k0 = 0; k0 < 64; k0 += 32) {
        {
            int row = tid >> 2, kq = tid & 3;
            short8 v = {0, 0, 0, 0, 0, 0, 0, 0};
            if (bm + row < nrows)
                v = *(const short8*)&X[(size_t)(bm + row) * 64 + k0 + kq * 8];
            *(short8*)&xs[row][kq * 8] = v;
        }
        {
            int c = tid >> 2, kq = tid & 3;
            *(short8*)&wt[c][kq * 8] = *(const short8*)&wt2[c * 64 + k0 + kq * 8];
        }
        __syncthreads();
        short8 af = *(short8*)&xs[wid * 16 + lr][lg * 8];
#pragma unroll
        for (int cb = 0; cb < 4; ++cb) {
            short8 bfb = *(short8*)&wt[cb * 16 + lr][lg * 8];
            acc[cb] = __builtin_amdgcn_mfma_f32_16x16x32_bf16(af, bfb, acc[cb], 0, 0, 0);
        }
        __syncthreads();
    }
#pragma unroll
    for (int cb = 0; cb < 4; ++cb)
#pragma unroll
        for (int r = 0; r < 4; ++r) {
            int m = bm + wid * 16 + lg * 4 + r;
            if (m < nrows) O[(size_t)m * 64 + cb * 16 + lr] = f2bf(acc[cb][r]);
        }
}

// ---------------- layer-1 attention coefficients (bf16 in, asrc bf16 out) ---
__global__ __launch_bounds__(256) void alpha1_kernel(const unsigned short* __restrict__ H1b,
                                                     const float* __restrict__ as1,
                                                     const float* __restrict__ ad1,
                                                     unsigned short* __restrict__ asrc,
                                                     float* __restrict__ adst, int n) {
    int idx = blockIdx.x * 256 + threadIdx.x;
    if (idx >= n * 8) return;
    int h = idx & 7;
    const unsigned short* hp = H1b + (size_t)(idx >> 3) * 64 + h * 8;
    short8 hv = *(const short8*)hp;
    float s = 0.f, d = 0.f;
#pragma unroll
    for (int c = 0; c < 8; ++c) {
        float v = bf2f((unsigned short)hv[c]);
        s = fmaf(v, as1[h * 8 + c], s);
        d = fmaf(v, ad1[h * 8 + c], d);
    }
    asrc[idx] = f2bf(s);
    adst[idx] = d;
}

// ---------------- layer-2 attention coefficients (wave per node) ------------
__global__ __launch_bounds__(256) void alpha2_kernel(const unsigned short* __restrict__ H2b,
                                                     const float* __restrict__ as2,
                                                     const float* __restrict__ ad2,
                                                     float* __restrict__ asrc,
                                                     float* __restrict__ adst, int n) {
    int node = blockIdx.x * 4 + (threadIdx.x >> 6);
    int lane = threadIdx.x & 63;
    if (node >= n) return;
    float v = bf2f(H2b[(size_t)node * 64 + lane]);
    float s = wred_sum(v * as2[lane]);
    float d = wred_sum(v * ad2[lane]);
    if (lane == 0) { asrc[node] = s; adst[node] = d; }
}

// ---------------- layer-1 aggregation: wave per dst node ----------------
__global__ __launch_bounds__(256) void agg1_kernel(const unsigned short* __restrict__ H1b,
                                                   const unsigned short* __restrict__ asrc,
                                                   const float* __restrict__ adst,
                                                   const int* __restrict__ rowptr,
                                                   const int* __restrict__ csrc,
                                                   const float* __restrict__ b1,
                                                   unsigned short* __restrict__ out1, int n) {
    __shared__ float wbuf[4][64][8];   // per-wave: 64 edges x 8 head-weights
    __shared__ int   sbuf[4][64];      // per-wave: 64 src ids
    int wid  = threadIdx.x >> 6;
    int lane = threadIdx.x & 63;
    int node = blockIdx.x * 4 + wid;
    if (node >= n) return;
    int h = lane >> 3;                 // head of this output channel
    int beg = rowptr[node], end = rowptr[node + 1];

    float ad[8];
    *(float4*)&ad[0] = *(const float4*)&adst[(size_t)node * 8];
    *(float4*)&ad[4] = *(const float4*)&adst[(size_t)node * 8 + 4];

    float lsum[8];
#pragma unroll
    for (int i = 0; i < 8; ++i) lsum[i] = 0.f;
    float acc0 = 0.f, acc1 = 0.f;

    for (int c0 = beg; c0 < end; c0 += 64) {
        int e = c0 + lane;
        if (e < end) {
            int s = csrc[e];
            sbuf[wid][lane] = s;
            short8 av = *(const short8*)&asrc[(size_t)s * 8];
            float p[8];
#pragma unroll
            for (int i = 0; i < 8; ++i) {
                float t = bf2f((unsigned short)av[i]) + ad[i];
                t = t > 0.f ? t : 0.2f * t;          // leaky_relu
                p[i] = __expf(t);                    // unnormalized weight
                lsum[i] += p[i];
            }
            *(float4*)&wbuf[wid][lane][0] = *(float4*)&p[0];
            *(float4*)&wbuf[wid][lane][4] = *(float4*)&p[4];
        }
        int cnt = min(64, end - c0);
        // gather-accumulate: independent iterations, 4-way unrolled
        int i = 0;
        for (; i + 3 < cnt; i += 4) {
            int s0 = sbuf[wid][i + 0], s1 = sbuf[wid][i + 1];
            int s2 = sbuf[wid][i + 2], s3 = sbuf[wid][i + 3];
            float w0 = wbuf[wid][i + 0][h], w1 = wbuf[wid][i + 1][h];
            float w2 = wbuf[wid][i + 2][h], w3 = wbuf[wid][i + 3][h];
            float g0 = bf2f(H1b[(size_t)s0 * 64 + lane]);
            float g1 = bf2f(H1b[(size_t)s1 * 64 + lane]);
            float g2 = bf2f(H1b[(size_t)s2 * 64 + lane]);
            float g3 = bf2f(H1b[(size_t)s3 * 64 + lane]);
            acc0 = fmaf(g0, w0, acc0);
            acc1 = fmaf(g1, w1, acc1);
            acc0 = fmaf(g2, w2, acc0);
            acc1 = fmaf(g3, w3, acc1);
        }
        for (; i < cnt; ++i) {
            int s   = sbuf[wid][i];
            float w = wbuf[wid][i][h];
            acc0 = fmaf(bf2f(H1b[(size_t)s * 64 + lane]), w, acc0);
        }
    }
    float acc = acc0 + acc1;
#pragma unroll
    for (int off = 32; off > 0; off >>= 1)
#pragma unroll
        for (int i = 0; i < 8; ++i) lsum[i] += __shfl_xor(lsum[i], off);
    float L = lsum[0];
#pragma unroll
    for (int i = 1; i < 8; ++i) if (h == i) L = lsum[i];   // compile-time idx
    float o = acc / (L + 1e-16f) + b1[lane];
    o = o > 0.f ? o : expm1f(o);                           // ELU
    out1[(size_t)node * 64 + lane] = f2bf(o);
}

// ---------------- layer-2 aggregation + log_softmax ----------------
__global__ __launch_bounds__(256) void agg2_kernel(const unsigned short* __restrict__ H2b,
                                                   const float* __restrict__ asrc,
                                                   const float* __restrict__ adst,
                                                   const int* __restrict__ rowptr,
                                                   const int* __restrict__ csrc,
                                                   const float* __restrict__ b2,
                                                   float* __restrict__ out, int n) {
    __shared__ float wbuf[4][64];
    __shared__ int   sbuf[4][64];
    int wid  = threadIdx.x >> 6;
    int lane = threadIdx.x & 63;
    int node = blockIdx.x * 4 + wid;
    if (node >= n) return;
    int beg = rowptr[node], end = rowptr[node + 1];
    float ad = adst[node];

    float lsum = 0.f, acc0 = 0.f, acc1 = 0.f;
    for (int c0 = beg; c0 < end; c0 += 64) {
        int e = c0 + lane;
        if (e < end) {
            int s = csrc[e];
            sbuf[wid][lane] = s;
            float t = asrc[s] + ad;
            t = t > 0.f ? t : 0.2f * t;
            float p = __expf(t);
            lsum += p;
            wbuf[wid][lane] = p;
        }
        int cnt = min(64, end - c0);
        int i = 0;
        for (; i + 3 < cnt; i += 4) {
            int s0 = sbuf[wid][i + 0], s1 = sbuf[wid][i + 1];
            int s2 = sbuf[wid][i + 2], s3 = sbuf[wid][i + 3];
            float w0 = wbuf[wid][i + 0], w1 = wbuf[wid][i + 1];
            float w2 = wbuf[wid][i + 2], w3 = wbuf[wid][i + 3];
            float g0 = bf2f(H2b[(size_t)s0 * 64 + lane]);
            float g1 = bf2f(H2b[(size_t)s1 * 64 + lane]);
            float g2 = bf2f(H2b[(size_t)s2 * 64 + lane]);
            float g3 = bf2f(H2b[(size_t)s3 * 64 + lane]);
            acc0 = fmaf(g0, w0, acc0);
            acc1 = fmaf(g1, w1, acc1);
            acc0 = fmaf(g2, w2, acc0);
            acc1 = fmaf(g3, w3, acc1);
        }
        for (; i < cnt; ++i) {
            acc0 = fmaf(bf2f(H2b[(size_t)sbuf[wid][i] * 64 + lane]), wbuf[wid][i], acc0);
        }
    }
    lsum = wred_sum(lsum);
    float o = (acc0 + acc1) / (lsum + 1e-16f) + b2[lane];
    float mx = wred_max(o);
    float se = wred_sum(__expf(o - mx));
    out[(size_t)node * 64 + lane] = o - mx - logf(se);
}

extern "C" void kernel_launch(void* const* d_in, const int* in_sizes, int n_in,
                              void* d_out, int out_size, void* d_ws, size_t ws_size,
                              hipStream_t stream) {
    const float* x   = (const float*)d_in[0];
    const int*   ei  = (const int*)d_in[1];
    const float* W1  = (const float*)d_in[2];
    const float* as1 = (const float*)d_in[3];
    const float* ad1 = (const float*)d_in[4];
    const float* b1  = (const float*)d_in[5];
    const float* W2  = (const float*)d_in[6];
    const float* as2 = (const float*)d_in[7];
    const float* ad2 = (const float*)d_in[8];
    const float* b2  = (const float*)d_in[9];
    float* out = (float*)d_out;

    const int n  = in_sizes[0] / 512;   // 50000
    const int E  = in_sizes[1] / 2;     // 1600000
    const int Et = E + n;
    const int NB  = (n + 127) >> NPB_SHIFT;       // 391 buckets
    const int epb = (Et + NBLK - 1) / NBLK;       // edges per P1/P3 block

    char* w = (char*)d_ws;
    auto alloc = [&](size_t bytes) {
        char* p = w;
        w += (bytes + 255) & ~(size_t)255;
        return p;
    };
    int*            hist   = (int*)alloc((size_t)NBLK * NB * 4);
    int*            bBase  = (int*)alloc((size_t)(NB + 1) * 4);
    unsigned*       region = (unsigned*)alloc((size_t)Et * 4);   // becomes csrc
    int*            rowptr = (int*)alloc((size_t)(n + 1) * 4);
    unsigned short* h1b    = (unsigned short*)alloc((size_t)n * 64 * 2);
    unsigned short* out1b  = (unsigned short*)alloc((size_t)n * 64 * 2);
    unsigned short* h2b    = (unsigned short*)alloc((size_t)n * 64 * 2);
    unsigned short* asrc1b = (unsigned short*)alloc((size_t)n * 8 * 2);
    float*          adst1  = (float*)alloc((size_t)n * 8 * 4);
    float*          asrc2  = (float*)alloc((size_t)n * 4);
    float*          adst2  = (float*)alloc((size_t)n * 4);
    unsigned short* wtg    = (unsigned short*)alloc((size_t)64 * 512 * 2);
    unsigned short* wtg2   = (unsigned short*)alloc((size_t)64 * 64 * 2);
    int*            csrc   = (int*)region;         // alias (see bucket_build)

    // --- CSR build (counting sort, no global atomics) ---
    bucket_count  <<<NBLK, 256, 0, stream>>>(ei, hist, E, Et, NB, epb);
    bucket_scan   <<<1,    512, 0, stream>>>(hist, bBase, rowptr, NB, NBLK, n);
    bucket_scatter<<<NBLK, 256, 0, stream>>>(ei, hist, region, E, Et, NB, epb);
    bucket_build  <<<NB,   256, 0, stream>>>(region, bBase, rowptr, n);

    // --- layer 1 ---
    wtrans_kernel<<<(64 * 512 + 255) / 256, 256, 0, stream>>>(W1, wtg);
    gemm1_mfma<<<(n + 63) / 64, 256, 0, stream>>>(x, wtg, h1b, n);
    alpha1_kernel<<<(n * 8 + 255) / 256, 256, 0, stream>>>(h1b, as1, ad1, asrc1b, adst1, n);
    agg1_kernel<<<(n + 3) / 4, 256, 0, stream>>>(h1b, asrc1b, adst1, rowptr, csrc, b1, out1b, n);

    // --- layer 2 ---
    wtrans2_kernel<<<(64 * 64 + 255) / 256, 256, 0, stream>>>(W2, wtg2);
    gemm2_mfma<<<(n + 63) / 64, 256, 0, stream>>>(out1b, wtg2, h2b, n);
    alpha2_kernel<<<(n + 3) / 4, 256, 0, stream>>>(h2b, as2, ad2, asrc2, adst2, n);
    agg2_kernel<<<(n + 3) / 4, 256, 0, stream>>>(h2b, asrc2, adst2, rowptr, csrc, b2, out, n);
}